// Round 8
// baseline (233.878 us; speedup 1.0000x reference)
//
#include <hip/hip_runtime.h>
#include <cmath>

#define BB 2
#define TT 2048
#define NN 16
#define DD 128
#define NROWS (BB*TT*NN)          // 65536 rows of 128
#define PLANE (TT*DD)             // elements per (b,n) plane
#define KP 132                    // Ks/Xs/Ws pitch (u16): 66 dw == 2 mod 32
#define VP 68                     // Vt pitch (u16): 34 dw == 2 mod 32

typedef unsigned short u16;
typedef unsigned int   u32;
typedef __attribute__((ext_vector_type(8)))  short s8v;   // 8 bf16 = 4 VGPRs
typedef __attribute__((ext_vector_type(16))) float vf16;  // MFMA 32x32 acc

// Static device-global scratch (no ws_size assumptions).
__device__ u16 g_Q [(size_t)NROWS * DD];   // (b,n,t,d) bf16; overwritten by att
__device__ u16 g_K [(size_t)NROWS * DD];   // (b,n,t,d) bf16
__device__ u16 g_VT[(size_t)NROWS * DD];   // (b,n,d,t) bf16 (written by qkv)
// split-K partials for heavy q-tiles (qt_h = 15-g, 8 per plane x 32 planes)
__device__ float g_pO[2][256][128*128];    // unnormalized O, fp32
__device__ float g_pm[2][256][128];        // running max (exp2 domain)
__device__ float g_pl[2][256][128];        // running denom

__device__ __forceinline__ u16 f2bf(float f) {
    return (u16)((__float_as_uint(f) + 0x8000u) >> 16);
}
__device__ __forceinline__ u32 pk2(float a, float b) {
    return ((__float_as_uint(a) + 0x8000u) >> 16)
         | ((__float_as_uint(b) + 0x8000u) & 0xFFFF0000u);
}
__device__ __forceinline__ void st8(u16* p, const float4& a, const float4& b) {
    uint2 lo, hi;
    lo.x = pk2(a.x, a.y); lo.y = pk2(a.z, a.w);
    hi.x = pk2(b.x, b.y); hi.y = pk2(b.z, b.w);
    *(uint2*)p       = lo;
    *(uint2*)(p + 4) = hi;
}
__device__ __forceinline__ s8v ld8(const u16* p) {      // two aligned b64 reads
    short4 a = *(const short4*)p;
    short4 b = *(const short4*)(p + 4);
    return (s8v){a.x, a.y, a.z, a.w, b.x, b.y, b.z, b.w};
}

// ---------------------------------------------------------------------------
// Fused QKV projection: x fp32 rows (b,t,n) -> bf16 Q/K rows (b,n,t) and V
// directly transposed into g_VT (b,n,d,t). Epilogue re-tiles C through the
// dead W LDS buffer so global stores are coalesced (256-B rows for Q/K).
// ---------------------------------------------------------------------------
__global__ __launch_bounds__(256)
void qkv_proj_kernel(const float* __restrict__ x,
                     const float* __restrict__ Wq, const float* __restrict__ Bq,
                     const float* __restrict__ Wk, const float* __restrict__ Bk,
                     const float* __restrict__ Wv, const float* __restrict__ Bv)
{
    __shared__ u16 Xs[128*KP];
    __shared__ u16 Ws[128*KP];   // W tile; reused as C tile in epilogue

    const int t  = threadIdx.x;
    const int r0 = blockIdx.x * 128;
    const float4* xsrc = (const float4*)(x + (size_t)r0*DD);

    #pragma unroll
    for (int it = 0; it < 8; ++it) {
        int i = t + 256*it;
        int e = i >> 4, c8 = i & 15;
        st8(&Xs[e*KP + c8*8], xsrc[2*i], xsrc[2*i + 1]);
        st8(&Ws[e*KP + c8*8], ((const float4*)Wq)[2*i], ((const float4*)Wq)[2*i + 1]);
    }
    __syncthreads();

    const int w   = t >> 6;
    const int l31 = t & 31;
    const int q2  = (t >> 5) & 1;

    s8v af[8];
    #pragma unroll
    for (int s = 0; s < 8; ++s)
        af[s] = ld8(&Xs[(w*32 + l31)*KP + s*16 + q2*8]);

    #pragma unroll
    for (int wsel = 0; wsel < 3; ++wsel) {
        const float* Bi = (wsel == 0) ? Bq : (wsel == 1) ? Bk : Bv;

        vf16 acc[4];
        #pragma unroll
        for (int et = 0; et < 4; ++et)
            #pragma unroll
            for (int i = 0; i < 16; ++i) acc[et][i] = 0.f;

        #pragma unroll
        for (int s = 0; s < 8; ++s) {
            #pragma unroll
            for (int et = 0; et < 4; ++et) {
                s8v bf = ld8(&Ws[(et*32 + l31)*KP + s*16 + q2*8]);
                acc[et] = __builtin_amdgcn_mfma_f32_32x32x16_bf16(af[s], bf, acc[et], 0, 0, 0);
            }
        }

        float bb[4];
        #pragma unroll
        for (int et = 0; et < 4; ++et) bb[et] = Bi[et*32 + l31];

        __syncthreads();             // all waves done reading W -> reuse as C
        if (wsel < 2) {
            // C[row][e] layout for coalesced row stores
            #pragma unroll
            for (int et = 0; et < 4; ++et)
                #pragma unroll
                for (int r = 0; r < 16; ++r) {
                    int rl = (r & 3) + 8*(r >> 2) + 4*q2;
                    Ws[(w*32 + rl)*KP + et*32 + l31] = f2bf(acc[et][r] + bb[et]);
                }
        } else {
            // C[d][row] layout (transposed) for VT stores
            #pragma unroll
            for (int et = 0; et < 4; ++et)
                #pragma unroll
                for (int r = 0; r < 16; ++r) {
                    int rl = (r & 3) + 8*(r >> 2) + 4*q2;
                    Ws[(et*32 + l31)*KP + w*32 + rl] = f2bf(acc[et][r] + bb[et]);
                }
        }
        __syncthreads();

        if (wsel < 2) {
            u16* Ot = (wsel == 0) ? g_Q : g_K;
            int row = t >> 1, half = t & 1;
            int rg = r0 + row;
            int b = rg >> 15, rem = rg & 32767;   // (b,t,n) -> (b,n,t)
            int tt = rem >> 4, n = rem & 15;
            u16* dst = Ot + (size_t)((b*NN + n)*TT + tt)*DD + half*64;
            const u16* src = &Ws[row*KP + half*64];
            #pragma unroll
            for (int j = 0; j < 8; ++j) {        // 8 x uint4 = 64 u16 (FIXED)
                uint2 a = ((const uint2*)src)[2*j];
                uint2 c = ((const uint2*)src)[2*j + 1];
                uint4 v; v.x = a.x; v.y = a.y; v.z = c.x; v.w = c.y;
                ((uint4*)dst)[j] = v;
            }
        } else {
            // scatter V^T: per (n,d) pack 8 consecutive t (16-B stores; adjacent
            // blocks' segments merge to full lines in L2)
            int b  = r0 >> 15;
            int t0 = (r0 & 32767) >> 4;           // 8-aligned t base
            #pragma unroll
            for (int it = 0; it < 8; ++it) {
                int idx = t + 256*it;             // 2048 = 16 n x 128 d
                int n = idx >> 7, d = idx & 127;
                u16 e[8];
                #pragma unroll
                for (int ti = 0; ti < 8; ++ti)
                    e[ti] = Ws[d*KP + ti*16 + n];
                uint4 pkv;
                pkv.x = (u32)e[0] | ((u32)e[1] << 16);
                pkv.y = (u32)e[2] | ((u32)e[3] << 16);
                pkv.z = (u32)e[4] | ((u32)e[5] << 16);
                pkv.w = (u32)e[6] | ((u32)e[7] << 16);
                *(uint4*)&g_VT[(size_t)(b*NN + n)*PLANE + (size_t)d*TT + t0] = pkv;
            }
        }

        if (wsel < 2) {
            const float* Wn = (wsel == 0) ? Wk : Wv;
            __syncthreads();         // epilogue done reading Ws
            #pragma unroll
            for (int it = 0; it < 8; ++it) {
                int i = t + 256*it;
                int e = i >> 4, c8 = i & 15;
                st8(&Ws[e*KP + c8*8], ((const float4*)Wn)[2*i], ((const float4*)Wn)[2*i + 1]);
            }
            __syncthreads();
        }
    }
}

// ---------------------------------------------------------------------------
// Output projection: bf16 att rows (b,n,t) in g_Q -> fp32 out rows (b,t,n).
// Epilogue re-tiles through LDS (two fp32 half-dumps) -> contiguous stores.
// ---------------------------------------------------------------------------
__global__ __launch_bounds__(256)
void out_proj_kernel(const float* __restrict__ W, const float* __restrict__ Bi,
                     float* __restrict__ out)
{
    __shared__ u16   Ws[128*KP];
    __shared__ float Cs[128*66];     // 64-d half of C, pitch 66 dw

    const int t  = threadIdx.x;
    const int r0 = blockIdx.x * 128;

    #pragma unroll
    for (int it = 0; it < 8; ++it) {
        int i = t + 256*it;
        int e = i >> 4, c8 = i & 15;
        st8(&Ws[e*KP + c8*8], ((const float4*)W)[2*i], ((const float4*)W)[2*i + 1]);
    }

    const int w   = t >> 6;
    const int l31 = t & 31;
    const int q2  = (t >> 5) & 1;

    s8v af[8];
    {
        const u16* src = g_Q + (size_t)(r0 + w*32 + l31)*DD;
        #pragma unroll
        for (int s = 0; s < 8; ++s)
            af[s] = *(const s8v*)&src[s*16 + q2*8];
    }
    __syncthreads();

    vf16 acc[4];
    #pragma unroll
    for (int et = 0; et < 4; ++et)
        #pragma unroll
        for (int i = 0; i < 16; ++i) acc[et][i] = 0.f;

    #pragma unroll
    for (int s = 0; s < 8; ++s) {
        #pragma unroll
        for (int et = 0; et < 4; ++et) {
            s8v bf = ld8(&Ws[(et*32 + l31)*KP + s*16 + q2*8]);
            acc[et] = __builtin_amdgcn_mfma_f32_32x32x16_bf16(af[s], bf, acc[et], 0, 0, 0);
        }
    }

    float bb[4];
    #pragma unroll
    for (int et = 0; et < 4; ++et) bb[et] = Bi[et*32 + l31];

    const int row  = t >> 1;
    const int seg  = t & 1;
    int rg = r0 + row;
    int b = rg >> 15, rem = rg & 32767;   // (b,n,t) -> (b,t,n)
    int n = rem >> 11, tt = rem & 2047;
    float* orow = out + (size_t)((b*TT + tt)*NN + n)*DD;

    #pragma unroll
    for (int h = 0; h < 2; ++h) {
        #pragma unroll
        for (int e2 = 0; e2 < 2; ++e2) {
            int et = 2*h + e2;
            #pragma unroll
            for (int r = 0; r < 16; ++r) {
                int rl = (r & 3) + 8*(r >> 2) + 4*q2;
                Cs[(w*32 + rl)*66 + e2*32 + l31] = acc[et][r] + bb[et];
            }
        }
        __syncthreads();
        {
            const float* src = &Cs[row*66 + seg*32];
            float* dst = orow + h*64 + seg*32;
            #pragma unroll
            for (int j = 0; j < 16; ++j) {   // 16 x float2 = 32 floats (FIXED)
                float2 v = ((const float2*)src)[j];
                ((float2*)dst)[j] = v;
            }
        }
        __syncthreads();
    }
}

// ---------------------------------------------------------------------------
// MFMA flash attention, uniform split-K. Pair (qt_h=15-g, qt_l=g) has 34
// kt-iters; sid=0 takes qt_h kts [0,17), sid=1 takes qt_h kts [17,nkt_h) then
// all of qt_l. Heavy tiles write 2 partials (unnormalized O + m,l) merged by
// combine_kernel; qt_l finalized in-kernel. Every block = exactly 17 iters.
// ---------------------------------------------------------------------------
__global__ __launch_bounds__(256, 2)
void attn_kernel()
{
    __shared__ u16 Ks[64*KP];
    __shared__ u16 Vt[128*VP];

    const int t    = threadIdx.x;
    const int pid  = blockIdx.x;
    const int bn   = pid & 31;
    const int sid  = (pid >> 5) & 1;
    const int g    = pid >> 6;            // 0..7
    const int qt_h = 15 - g;
    const int nkt_h = 2*qt_h + 2;
    const int qt_l = g;
    const int hidx = g*32 + bn;

    const size_t plane = (size_t)bn * PLANE;
    const u16* Kg = g_K  + plane;
    const u16* Vg = g_VT + plane;

    const int w      = t >> 6;
    const int lane   = t & 63;
    const int lane31 = lane & 31;
    const int q2     = lane >> 5;

    int qband = qt_h*128 + 32*w;
    int qrow  = qband + lane31;

    s8v qf[8];
    {
        const u16* Qg = g_Q + plane + (size_t)qrow * DD;
        #pragma unroll
        for (int s = 0; s < 8; ++s)
            qf[s] = *(const s8v*)&Qg[s*16 + q2*8];
    }

    vf16 accO[4];
    #pragma unroll
    for (int dt = 0; dt < 4; ++dt)
        #pragma unroll
        for (int i = 0; i < 16; ++i) accO[dt][i] = 0.f;

    float mrow = -INFINITY, lrow = 0.f;
    const float sc2 = 0.08838834764831845f * 1.4426950408889634f; // exp2 domain

    const int ph1n = (sid == 0) ? 17 : (nkt_h - 17);   // iters in phase 1

    auto K0 = [&](int i) -> int {
        if (sid == 0) return i*64;
        return (i < ph1n) ? (17 + i)*64 : (i - ph1n)*64;
    };

    // prefetch tile 0
    uint4 pk[4], pv[4];
    {
        const u16* Kg2 = Kg + (size_t)K0(0)*DD;
        const u16* Vg2 = Vg + K0(0);
        #pragma unroll
        for (int c = 0; c < 4; ++c) {
            int j = t + 256*c;
            int kr = j >> 4, kc = j & 15;
            pk[c] = *(const uint4*)&Kg2[kr*DD + kc*8];
            int vr = j >> 3, vc = j & 7;
            pv[c] = *(const uint4*)&Vg2[(size_t)vr*TT + vc*8];
        }
    }

    for (int i = 0; i < 17; ++i) {
        const int k0 = K0(i);

        // phase transition (sid=1 only): flush qt_h partial, switch to qt_l
        if (sid == 1 && i == ph1n) {
            if (lane < 32) {
                g_pm[1][hidx][32*w + lane31] = mrow;
                g_pl[1][hidx][32*w + lane31] = lrow;
            }
            float* po = &g_pO[1][hidx][0];
            #pragma unroll
            for (int r = 0; r < 16; ++r) {
                int rl = (r & 3) + 8*(r >> 2) + 4*q2;
                float* dst = po + (32*w + rl)*128;
                #pragma unroll
                for (int dt = 0; dt < 4; ++dt)
                    dst[dt*32 + lane31] = accO[dt][r];
            }
            qband = qt_l*128 + 32*w;
            qrow  = qband + lane31;
            const u16* Qg = g_Q + plane + (size_t)qrow * DD;
            #pragma unroll
            for (int s = 0; s < 8; ++s)
                qf[s] = *(const s8v*)&Qg[s*16 + q2*8];
            #pragma unroll
            for (int dt = 0; dt < 4; ++dt)
                #pragma unroll
                for (int r = 0; r < 16; ++r) accO[dt][r] = 0.f;
            mrow = -INFINITY; lrow = 0.f;
        }

        __syncthreads();                          // prev iter done with LDS
        #pragma unroll
        for (int c = 0; c < 4; ++c) {
            int j = t + 256*c;
            int kr = j >> 4, kc = j & 15;
            uint2 a, b;
            a.x = pk[c].x; a.y = pk[c].y; b.x = pk[c].z; b.y = pk[c].w;
            *(uint2*)&Ks[kr*KP + kc*8]     = a;
            *(uint2*)&Ks[kr*KP + kc*8 + 4] = b;
            int vr = j >> 3, vc = j & 7;
            a.x = pv[c].x; a.y = pv[c].y; b.x = pv[c].z; b.y = pv[c].w;
            *(uint2*)&Vt[vr*VP + vc*8]     = a;
            *(uint2*)&Vt[vr*VP + vc*8 + 4] = b;
        }
        __syncthreads();

        if (i + 1 < 17) {
            const int kn = K0(i + 1);
            const u16* Kg2 = Kg + (size_t)kn*DD;
            const u16* Vg2 = Vg + kn;
            #pragma unroll
            for (int c = 0; c < 4; ++c) {
                int j = t + 256*c;
                int kr = j >> 4, kc = j & 15;
                pk[c] = *(const uint4*)&Kg2[kr*DD + kc*8];
                int vr = j >> 3, vc = j & 7;
                pv[c] = *(const uint4*)&Vg2[(size_t)vr*TT + vc*8];
            }
        }

        if (k0 > qband + 31) continue;            // fully masked for this wave

        // ---- S^T = K · Q^T ----
        vf16 accS[2];
        #pragma unroll
        for (int kk = 0; kk < 2; ++kk)
            #pragma unroll
            for (int i2 = 0; i2 < 16; ++i2) accS[kk][i2] = 0.f;
        #pragma unroll
        for (int s = 0; s < 8; ++s) {
            #pragma unroll
            for (int kk = 0; kk < 2; ++kk) {
                s8v a = ld8(&Ks[(kk*32 + lane31)*KP + s*16 + q2*8]);
                accS[kk] = __builtin_amdgcn_mfma_f32_32x32x16_bf16(a, qf[s], accS[kk], 0, 0, 0);
            }
        }

        // ---- scale (exp2 domain) + causal mask ----
        float p[2][16];
        const bool tail = (k0 + 63 > qband);
        #pragma unroll
        for (int kk = 0; kk < 2; ++kk)
            #pragma unroll
            for (int r = 0; r < 16; ++r) {
                float sv = accS[kk][r] * sc2;
                if (tail) {
                    int keyg = k0 + kk*32 + (r & 3) + 8*(r >> 2) + 4*q2;
                    if (keyg > qrow) sv = -INFINITY;
                }
                p[kk][r] = sv;
            }

        // ---- online softmax (per-lane scalar m/l, one q-col) ----
        float vmax = -INFINITY;
        #pragma unroll
        for (int kk = 0; kk < 2; ++kk)
            #pragma unroll
            for (int r = 0; r < 16; ++r) vmax = fmaxf(vmax, p[kk][r]);
        vmax = fmaxf(vmax, __shfl_xor(vmax, 32));
        float mold = mrow;
        float mnew = fmaxf(mold, vmax);
        float alpha = __builtin_amdgcn_exp2f(mold - mnew);
        mrow = mnew;
        float ls = 0.f;
        #pragma unroll
        for (int kk = 0; kk < 2; ++kk)
            #pragma unroll
            for (int r = 0; r < 16; ++r) {
                float e = __builtin_amdgcn_exp2f(p[kk][r] - mnew);
                p[kk][r] = e;
                ls += e;
            }
        ls += __shfl_xor(ls, 32);
        lrow = lrow*alpha + ls;

        if (__any(mnew > mold)) {
            float ar[16];
            #pragma unroll
            for (int r = 0; r < 16; ++r)
                ar[r] = __shfl(alpha, (r & 3) + 8*(r >> 2) + 4*q2);
            #pragma unroll
            for (int dt = 0; dt < 4; ++dt)
                #pragma unroll
                for (int r = 0; r < 16; ++r) accO[dt][r] *= ar[r];
        }

        // ---- pack P (bf16 trunc) as PV A-fragments ----
        s8v pf[4];
        #pragma unroll
        for (int tau = 0; tau < 4; ++tau) {
            int kk = tau >> 1, rb = (tau & 1)*8;
            s8v v;
            #pragma unroll
            for (int j = 0; j < 8; ++j)
                v[j] = (short)(__float_as_uint(p[kk][rb + j]) >> 16);
            pf[tau] = v;
        }

        // ---- O += P · V ----
        #pragma unroll
        for (int dt = 0; dt < 4; ++dt) {
            const u16* vp = &Vt[(dt*32 + lane31)*VP];
            #pragma unroll
            for (int tau = 0; tau < 4; ++tau) {
                const u16* q = vp + 16*tau + 4*q2;
                short4 lo = *(const short4*)q;
                short4 hi = *(const short4*)(q + 8);
                s8v bvv = {lo.x, lo.y, lo.z, lo.w, hi.x, hi.y, hi.z, hi.w};
                accO[dt] = __builtin_amdgcn_mfma_f32_32x32x16_bf16(pf[tau], bvv, accO[dt], 0, 0, 0);
            }
        }
    }

    if (sid == 0) {
        // flush qt_h partial slot 0
        if (lane < 32) {
            g_pm[0][hidx][32*w + lane31] = mrow;
            g_pl[0][hidx][32*w + lane31] = lrow;
        }
        float* po = &g_pO[0][hidx][0];
        #pragma unroll
        for (int r = 0; r < 16; ++r) {
            int rl = (r & 3) + 8*(r >> 2) + 4*q2;
            float* dst = po + (32*w + rl)*128;
            #pragma unroll
            for (int dt = 0; dt < 4; ++dt)
                dst[dt*32 + lane31] = accO[dt][r];
        }
    } else {
        // finalize qt_l: normalize, write bf16 over own g_Q rows
        float inv = 1.0f / lrow;
        #pragma unroll
        for (int r = 0; r < 16; ++r) {
            int rl = (r & 3) + 8*(r >> 2) + 4*q2;
            float ir = __shfl(inv, rl);
            u16* op = g_Q + plane + (size_t)(qband + rl)*DD;
            #pragma unroll
            for (int dt = 0; dt < 4; ++dt)
                op[dt*32 + lane31] = f2bf(accO[dt][r] * ir);
        }
    }
}

// ---------------------------------------------------------------------------
// Combine the two partials of each heavy q-tile -> bf16 into g_Q.
// ---------------------------------------------------------------------------
__global__ __launch_bounds__(256)
void combine_kernel()
{
    const int hidx = blockIdx.x;          // 0..255
    const int g    = hidx >> 5;
    const int bn   = hidx & 31;
    const int qt_h = 15 - g;

    const int t    = threadIdx.x;
    const int row  = t >> 1;
    const int half = t & 1;

    float m1 = g_pm[0][hidx][row], l1 = g_pl[0][hidx][row];
    float m2 = g_pm[1][hidx][row], l2 = g_pl[1][hidx][row];
    float m  = fmaxf(m1, m2);
    float a1 = __builtin_amdgcn_exp2f(m1 - m);
    float a2 = __builtin_amdgcn_exp2f(m2 - m);
    float inv = 1.0f / (a1*l1 + a2*l2);
    a1 *= inv; a2 *= inv;

    const float* O1 = &g_pO[0][hidx][row*128 + half*64];
    const float* O2 = &g_pO[1][hidx][row*128 + half*64];
    u16* dst = g_Q + (size_t)bn*PLANE + (size_t)(qt_h*128 + row)*DD + half*64;

    #pragma unroll
    for (int j = 0; j < 16; ++j) {
        float4 u = ((const float4*)O1)[j];
        float4 v = ((const float4*)O2)[j];
        float o0 = a1*u.x + a2*v.x;
        float o1 = a1*u.y + a2*v.y;
        float o2 = a1*u.z + a2*v.z;
        float o3 = a1*u.w + a2*v.w;
        uint2 pw; pw.x = pk2(o0, o1); pw.y = pk2(o2, o3);
        ((uint2*)dst)[j] = pw;
    }
}

extern "C" void kernel_launch(void* const* d_in, const int* in_sizes, int n_in,
                              void* d_out, int out_size, void* d_ws, size_t ws_size,
                              hipStream_t stream)
{
    const float* x  = (const float*)d_in[0];
    const float* wq = (const float*)d_in[1];
    const float* bq = (const float*)d_in[2];
    const float* wk = (const float*)d_in[3];
    const float* bk = (const float*)d_in[4];
    const float* wv = (const float*)d_in[5];
    const float* bv = (const float*)d_in[6];
    const float* wp = (const float*)d_in[7];
    const float* bp = (const float*)d_in[8];
    float* out = (float*)d_out;
    (void)d_ws; (void)ws_size;

    dim3 blk(256);
    qkv_proj_kernel<<<dim3(NROWS/128), blk, 0, stream>>>(
        x, wq, bq, wk, bk, wv, bv);
    attn_kernel<<<dim3(512), blk, 0, stream>>>();
    combine_kernel<<<dim3(256), blk, 0, stream>>>();
    out_proj_kernel<<<dim3(NROWS/128), blk, 0, stream>>>(wp, bp, out);
}